// Round 10
// baseline (1036.027 us; speedup 1.0000x reference)
//
#include <hip/hip_runtime.h>
#include <hip/hip_bf16.h>
#include <math.h>

#define T_   64
#define B_   2048
#define OBS_ 48
#define H_   256
#define M1_  512
#define M2_  256
#define A_   12
#define BH_  (B_ * H_)
#define KP_  320   // padded K for scan: 64 (x, padded from 48) + 256 (h)

typedef unsigned short u16;
typedef __attribute__((ext_vector_type(8))) short bf16x8;
typedef __attribute__((ext_vector_type(4))) float f32x4;

static __device__ __forceinline__ u16 f2b(float f) {
    __hip_bfloat16 h = __float2bfloat16(f);
    return *reinterpret_cast<u16*>(&h);
}
static __device__ __forceinline__ float b2f(u16 u) {
    union { unsigned u32v; float f; } v; v.u32v = ((unsigned)u) << 16; return v.f;
}
static __device__ __forceinline__ float sigm(float x) {
    return 1.0f / (1.0f + __expf(-x));
}
static __device__ __forceinline__ float tanh_fast(float x) {
    x = fminf(fmaxf(x, -15.0f), 15.0f);
    float e = __expf(2.0f * x);
    return (e - 1.0f) / (e + 1.0f);
}
static __device__ __forceinline__ float elu(float x) {
    return x > 0.0f ? x : (__expf(x) - 1.0f);
}

// ---------------------------------------------------------------------------
// Pre-pass kernels
// ---------------------------------------------------------------------------
__global__ void prep_xpad(const float* __restrict__ x, u16* __restrict__ xpad) {
    const int gid = blockIdx.x * 256 + threadIdx.x;   // T*B*8 threads
    const int r = gid >> 3, k0 = (gid & 7) * 8;
    u16 tmp[8];
    if (k0 < OBS_) {
        const float4 f0 = *(const float4*)(x + (size_t)r * OBS_ + k0);
        const float4 f1 = *(const float4*)(x + (size_t)r * OBS_ + k0 + 4);
        tmp[0] = f2b(f0.x); tmp[1] = f2b(f0.y); tmp[2] = f2b(f0.z); tmp[3] = f2b(f0.w);
        tmp[4] = f2b(f1.x); tmp[5] = f2b(f1.y); tmp[6] = f2b(f1.z); tmp[7] = f2b(f1.w);
    } else {
        #pragma unroll
        for (int i = 0; i < 8; ++i) tmp[i] = 0;
    }
    *(uint4*)(xpad + (size_t)gid * 8) = *(uint4*)tmp;
}

__global__ void prep_weights(const float* __restrict__ W_ih, const float* __restrict__ W_hh,
                             const float* __restrict__ W1,  const float* __restrict__ W2,
                             const float* __restrict__ Wm,  const float* __restrict__ Ws,
                             u16* __restrict__ Wcat, u16* __restrict__ W1T,
                             u16* __restrict__ W2T,  u16* __restrict__ WhT) {
    const int b = blockIdx.x, tid = threadIdx.x;
    if (b < 1024) {
        for (int k = tid; k < KP_; k += 256) {
            float v;
            if (k < OBS_)    v = W_ih[b * OBS_ + k];
            else if (k < 64) v = 0.0f;
            else             v = W_hh[b * H_ + (k - 64)];
            Wcat[b * KP_ + k] = f2b(v);
        }
    } else if (b < 1536) {
        const int n = b - 1024;                       // W1T [512][256]
        W1T[n * 256 + tid] = f2b(W1[tid * M1_ + n]);
    } else if (b < 1792) {
        const int n = b - 1536;                       // W2T [256][512]
        W2T[n * 512 + tid]       = f2b(W2[tid * M2_ + n]);
        W2T[n * 512 + tid + 256] = f2b(W2[(tid + 256) * M2_ + n]);
    } else {
        const int n = b - 1792;                       // WhT [32][256]
        float v = 0.0f;
        if (n < 12)                 v = Wm[tid * A_ + n];
        else if (n >= 16 && n < 28) v = Ws[tid * A_ + (n - 16)];
        WhT[n * 256 + tid] = f2b(v);
    }
}

__global__ void init_state2(const float* __restrict__ h0, const float* __restrict__ c0,
                            u16* __restrict__ hs0, float* __restrict__ Cst) {
    const int i = blockIdx.x * 256 + threadIdx.x;
    hs0[i] = f2b(h0[i]);
    Cst[i] = c0[i];
}

// ---------------------------------------------------------------------------
// LSTM step (round-4/7 kernel, known-good ~11.25 us/step incl. dispatch).
// Grid (32,16): block = 64 b-rows x (4 gates x 16 j), 4 waves of 32x32.
// ---------------------------------------------------------------------------
#define ASM_(row, chunk) (a_sm + (size_t)(row) * 320 + (size_t)(((chunk) ^ ((row) & 7)) << 3))

__global__ __launch_bounds__(256, 2) void lstm_step4(
    const u16*  __restrict__ xpad_t,  // [B][64]
    const int*  __restrict__ done_t,  // [B]
    const u16*  __restrict__ Hin,     // [B][256] bf16
    u16*        __restrict__ Hout,    // [B][256] bf16
    float*      __restrict__ Cst,     // [B][256] fp32, in-place
    const u16*  __restrict__ Wcat,    // [1024][320]
    const float* __restrict__ b_ih,
    const float* __restrict__ b_hh)
{
    __shared__ u16   a_sm[64 * 320];   // 40 KB, XOR-swizzled
    __shared__ float g_sm[64][68];     // 17.4 KB
    __shared__ float keep_sm[64];

    const int tid  = threadIdx.x;
    const int lane = tid & 63;
    const int wave = tid >> 6;
    const int wm = wave & 1, wn = wave >> 1;
    const int quad = lane >> 4, l16 = lane & 15;
    const int b0 = blockIdx.x * 64;
    const int j0 = blockIdx.y * 16;

    // ---- preload B fragments (20 frags = 80 VGPRs; Wcat is L2-resident) ----
    bf16x8 Bf0[10], Bf1[10];
    {
        const u16* wp0 = Wcat + ((size_t)((wn * 2 + 0) * 256 + j0 + l16)) * KP_ + quad * 8;
        const u16* wp1 = Wcat + ((size_t)((wn * 2 + 1) * 256 + j0 + l16)) * KP_ + quad * 8;
        #pragma unroll
        for (int kt = 0; kt < 10; ++kt) {
            Bf0[kt] = *(const bf16x8*)(wp0 + kt * 32);
            Bf1[kt] = *(const bf16x8*)(wp1 + kt * 32);
        }
    }

    // ---- stage A tile: whole K=320 in one shot ----
    if (tid < 64) keep_sm[tid] = done_t[b0 + tid] ? 0.0f : 1.0f;
    {
        const int srow = tid >> 2;     // 0..63
        const int sseg = tid & 3;      // 0..3
        const u16* xrow = xpad_t + (size_t)(b0 + srow) * 64;
        const uint4 xv0 = *(const uint4*)(xrow + sseg * 8);
        const uint4 xv1 = *(const uint4*)(xrow + (sseg + 4) * 8);
        *(uint4*)ASM_(srow, sseg)     = xv0;
        *(uint4*)ASM_(srow, sseg + 4) = xv1;

        const int dn = done_t[b0 + srow];
        const u16* hrow = Hin + (size_t)(b0 + srow) * H_ + sseg * 64;
        #pragma unroll
        for (int i = 0; i < 8; ++i) {
            uint4 hv = *(const uint4*)(hrow + i * 8);
            if (dn) hv = make_uint4(0u, 0u, 0u, 0u);
            *(uint4*)ASM_(srow, 8 + sseg * 8 + i) = hv;
        }
    }
    __syncthreads();

    // ---- 40 MFMA per wave ----
    f32x4 acc00 = {0,0,0,0}, acc01 = {0,0,0,0}, acc10 = {0,0,0,0}, acc11 = {0,0,0,0};
    #pragma unroll
    for (int kt = 0; kt < 10; ++kt) {
        const bf16x8 af0 = *(const bf16x8*)ASM_(wm * 32 +  0 + l16, kt * 4 + quad);
        const bf16x8 af1 = *(const bf16x8*)ASM_(wm * 32 + 16 + l16, kt * 4 + quad);
        acc00 = __builtin_amdgcn_mfma_f32_16x16x32_bf16(af0, Bf0[kt], acc00, 0, 0, 0);
        acc01 = __builtin_amdgcn_mfma_f32_16x16x32_bf16(af0, Bf1[kt], acc01, 0, 0, 0);
        acc10 = __builtin_amdgcn_mfma_f32_16x16x32_bf16(af1, Bf0[kt], acc10, 0, 0, 0);
        acc11 = __builtin_amdgcn_mfma_f32_16x16x32_bf16(af1, Bf1[kt], acc11, 0, 0, 0);
    }

    // ---- accs -> LDS for cross-wave gate fusion ----
    #pragma unroll
    for (int r = 0; r < 4; ++r) {
        g_sm[wm * 32 +  0 + quad * 4 + r][wn * 32 +  0 + l16] = acc00[r];
        g_sm[wm * 32 +  0 + quad * 4 + r][wn * 32 + 16 + l16] = acc01[r];
        g_sm[wm * 32 + 16 + quad * 4 + r][wn * 32 +  0 + l16] = acc10[r];
        g_sm[wm * 32 + 16 + quad * 4 + r][wn * 32 + 16 + l16] = acc11[r];
    }
    __syncthreads();

    // ---- epilogue: gates -> c (fp32 global), h -> Hout (bf16) ----
    const int jj = tid & 15, bq = tid >> 4;
    const int jg = j0 + jj;
    const float bi_b = b_ih[jg]       + b_hh[jg];
    const float bf_b = b_ih[256 + jg] + b_hh[256 + jg];
    const float bg_b = b_ih[512 + jg] + b_hh[512 + jg];
    const float bo_b = b_ih[768 + jg] + b_hh[768 + jg];
    #pragma unroll
    for (int r = 0; r < 4; ++r) {
        const int b = bq * 4 + r;
        const float gi = g_sm[b][jj]      + bi_b;
        const float gf = g_sm[b][16 + jj] + bf_b;
        const float gg = g_sm[b][32 + jj] + bg_b;
        const float go = g_sm[b][48 + jj] + bo_b;
        const size_t idx = (size_t)(b0 + b) * H_ + jg;
        const float cold = Cst[idx] * keep_sm[b];
        const float cn = sigm(gf) * cold + sigm(gi) * tanh_fast(gg);
        Cst[idx] = cn;
        Hout[idx] = f2b(sigm(go) * tanh_fast(cn));
    }
}

// ---------------------------------------------------------------------------
// MLP v4: 64 rows/block, 512 threads, two-phase y1.
// Round 10 fix: ROTATION LDS swizzle (chunk' = (chunk+row)&31). Round 7's SY
// XOR swizzle was broken (row stride 512 B == bank 0; XOR permutes within the
// same bank residue) -> 8.79M bank conflicts made the LDS pipe the
// bottleneck (MfmaUtil 12.8%). Rotation gives uniform bank spread for both
// the A-frag ds_read_b128 pattern and the LN ushort4 writes.
// ---------------------------------------------------------------------------
#define SR(row, col) ((size_t)(row) * 256 + (size_t)(((((col) >> 3) + (row)) & 31) << 3) + ((col) & 7))

__global__ __launch_bounds__(512, 4) void mlp_mfma64(
    const u16*  __restrict__ hs,    // [nrows][256] bf16
    float*      __restrict__ out,   // [nrows][14]
    const float* __restrict__ lng, const float* __restrict__ lnb,
    const u16*  __restrict__ W1T, const float* __restrict__ b1,
    const u16*  __restrict__ W2T, const float* __restrict__ b2,
    const u16*  __restrict__ WhT,
    const float* __restrict__ bm, const float* __restrict__ bs)
{
    __shared__ u16 ybf[64 * 256];   // 32 KB: LN output, later y2
    __shared__ u16 yh [64 * 256];   // 32 KB: y1 column-half; later ls overlay

    const int tid  = threadIdx.x;
    const int lane = tid & 63;
    const int wave = tid >> 6;        // 0..7
    const int quad = lane >> 4, l16 = lane & 15;
    const int row0 = blockIdx.x * 64;

    // ---- LayerNorm: wave w -> rows w*8..w*8+7; lane holds 4 cols ----
    {
        const float4 gv = *(const float4*)(lng + lane * 4);
        const float4 bv = *(const float4*)(lnb + lane * 4);
        #pragma unroll
        for (int rr = 0; rr < 8; ++rr) {
            const int r = wave * 8 + rr;
            const ushort4 hv = *(const ushort4*)(hs + (size_t)(row0 + r) * H_ + lane * 4);
            const float v0 = b2f(hv.x), v1 = b2f(hv.y), v2 = b2f(hv.z), v3 = b2f(hv.w);
            float s  = v0 + v1 + v2 + v3;
            float ss = v0 * v0 + v1 * v1 + v2 * v2 + v3 * v3;
            #pragma unroll
            for (int off = 32; off > 0; off >>= 1) {
                s  += __shfl_down(s,  off);
                ss += __shfl_down(ss, off);
            }
            s = __shfl(s, 0); ss = __shfl(ss, 0);
            const float mu   = s * (1.0f / 256.0f);
            const float rstd = rsqrtf(ss * (1.0f / 256.0f) - mu * mu + 1e-5f);
            ushort4 o;
            o.x = f2b((v0 - mu) * rstd * gv.x + bv.x);
            o.y = f2b((v1 - mu) * rstd * gv.y + bv.y);
            o.z = f2b((v2 - mu) * rstd * gv.z + bv.z);
            o.w = f2b((v3 - mu) * rstd * gv.w + bv.w);
            *(ushort4*)(ybf + SR(r, lane * 4)) = o;
        }
    }
    __syncthreads();

    // ---- L2 partial accumulators: live across both phases ----
    f32x4 acc2[4][2];
    #pragma unroll
    for (int m = 0; m < 4; ++m)
        #pragma unroll
        for (int j = 0; j < 2; ++j) acc2[m][j] = (f32x4){0,0,0,0};

    #pragma unroll
    for (int ph = 0; ph < 2; ++ph) {
        // ---- L1 phase: y1 cols [ph*256 + wave*32, +32); ring-3 W prefetch ----
        {
            f32x4 acc[4][2];
            #pragma unroll
            for (int m = 0; m < 4; ++m)
                #pragma unroll
                for (int j = 0; j < 2; ++j) acc[m][j] = (f32x4){0,0,0,0};
            const int n0 = ph * 256 + wave * 32;
            const u16* wp0 = W1T + (size_t)(n0 + l16) * 256 + quad * 8;
            const u16* wp1 = W1T + (size_t)(n0 + 16 + l16) * 256 + quad * 8;
            bf16x8 w0[3], w1[3];
            w0[0] = *(const bf16x8*)(wp0);      w1[0] = *(const bf16x8*)(wp1);
            w0[1] = *(const bf16x8*)(wp0 + 32); w1[1] = *(const bf16x8*)(wp1 + 32);
            #pragma unroll
            for (int kt = 0; kt < 8; ++kt) {
                const int k0 = kt * 32;
                if (kt < 6) {
                    w0[(kt + 2) % 3] = *(const bf16x8*)(wp0 + k0 + 64);
                    w1[(kt + 2) % 3] = *(const bf16x8*)(wp1 + k0 + 64);
                }
                const bf16x8 bw0 = w0[kt % 3], bw1 = w1[kt % 3];
                #pragma unroll
                for (int m = 0; m < 4; ++m) {
                    const bf16x8 af = *(const bf16x8*)(ybf + SR(m * 16 + l16, k0 + quad * 8));
                    acc[m][0] = __builtin_amdgcn_mfma_f32_16x16x32_bf16(af, bw0, acc[m][0], 0, 0, 0);
                    acc[m][1] = __builtin_amdgcn_mfma_f32_16x16x32_bf16(af, bw1, acc[m][1], 0, 0, 0);
                }
            }
            const float bb0 = b1[n0 + l16], bb1 = b1[n0 + 16 + l16];
            __syncthreads();   // yh free (prev phase consumed / first use)
            #pragma unroll
            for (int m = 0; m < 4; ++m)
                #pragma unroll
                for (int r = 0; r < 4; ++r) {
                    const int row = m * 16 + quad * 4 + r;
                    yh[SR(row, wave * 32 + l16)]      = f2b(elu(acc[m][0][r] + bb0));
                    yh[SR(row, wave * 32 + 16 + l16)] = f2b(elu(acc[m][1][r] + bb1));
                }
        }
        __syncthreads();

        // ---- L2 partial: K in [ph*256, +256); ring-3 W prefetch ----
        {
            const int n0 = wave * 32;
            const u16* wp0 = W2T + (size_t)(n0 + l16) * 512 + ph * 256 + quad * 8;
            const u16* wp1 = W2T + (size_t)(n0 + 16 + l16) * 512 + ph * 256 + quad * 8;
            bf16x8 w0[3], w1[3];
            w0[0] = *(const bf16x8*)(wp0);      w1[0] = *(const bf16x8*)(wp1);
            w0[1] = *(const bf16x8*)(wp0 + 32); w1[1] = *(const bf16x8*)(wp1 + 32);
            #pragma unroll
            for (int kt = 0; kt < 8; ++kt) {
                const int k0 = kt * 32;
                if (kt < 6) {
                    w0[(kt + 2) % 3] = *(const bf16x8*)(wp0 + k0 + 64);
                    w1[(kt + 2) % 3] = *(const bf16x8*)(wp1 + k0 + 64);
                }
                const bf16x8 bw0 = w0[kt % 3], bw1 = w1[kt % 3];
                #pragma unroll
                for (int m = 0; m < 4; ++m) {
                    const bf16x8 af = *(const bf16x8*)(yh + SR(m * 16 + l16, k0 + quad * 8));
                    acc2[m][0] = __builtin_amdgcn_mfma_f32_16x16x32_bf16(af, bw0, acc2[m][0], 0, 0, 0);
                    acc2[m][1] = __builtin_amdgcn_mfma_f32_16x16x32_bf16(af, bw1, acc2[m][1], 0, 0, 0);
                }
            }
        }
        __syncthreads();
    }

    // ---- y2 = elu(acc2 + b2) -> ybf (LN data fully consumed) ----
    {
        const float bb0 = b2[wave * 32 + l16], bb1 = b2[wave * 32 + 16 + l16];
        #pragma unroll
        for (int m = 0; m < 4; ++m)
            #pragma unroll
            for (int r = 0; r < 4; ++r) {
                const int row = m * 16 + quad * 4 + r;
                ybf[SR(row, wave * 32 + l16)]      = f2b(elu(acc2[m][0][r] + bb0));
                ybf[SR(row, wave * 32 + 16 + l16)] = f2b(elu(acc2[m][1][r] + bb1));
            }
    }
    __syncthreads();

    // ---- Heads: waves 0..3 -> m-frag = wave; ring-3 prefetch ----
    float* lsf = (float*)yh;   // overlay: [64][16] floats (yh free)
    if (wave < 4) {
        f32x4 a0 = {0,0,0,0}, a1 = {0,0,0,0};
        const u16* wp0 = WhT + (size_t)l16 * 256 + quad * 8;          // mean rows
        const u16* wp1 = WhT + (size_t)(16 + l16) * 256 + quad * 8;   // logstd rows
        bf16x8 w0[3], w1[3];
        w0[0] = *(const bf16x8*)(wp0);      w1[0] = *(const bf16x8*)(wp1);
        w0[1] = *(const bf16x8*)(wp0 + 32); w1[1] = *(const bf16x8*)(wp1 + 32);
        #pragma unroll
        for (int kt = 0; kt < 8; ++kt) {
            const int k0 = kt * 32;
            if (kt < 6) {
                w0[(kt + 2) % 3] = *(const bf16x8*)(wp0 + k0 + 64);
                w1[(kt + 2) % 3] = *(const bf16x8*)(wp1 + k0 + 64);
            }
            const bf16x8 af = *(const bf16x8*)(ybf + SR(wave * 16 + l16, k0 + quad * 8));
            a0 = __builtin_amdgcn_mfma_f32_16x16x32_bf16(af, w0[kt % 3], a0, 0, 0, 0);
            a1 = __builtin_amdgcn_mfma_f32_16x16x32_bf16(af, w1[kt % 3], a1, 0, 0, 0);
        }
        if (l16 < 12) {
            const float bbm = bm[l16], bbs = bs[l16];
            #pragma unroll
            for (int r = 0; r < 4; ++r) {
                const int row = wave * 16 + quad * 4 + r;
                out[(size_t)(row0 + row) * 14 + l16] = a0[r] + bbm;
                lsf[row * 16 + l16] = fminf(fmaxf(a1[r] + bbs, -5.0f), 2.0f);
            }
        }
    }
    __syncthreads();
    if (tid < 64) {
        float s = 0.0f;
        #pragma unroll
        for (int q = 0; q < 12; ++q) s += lsf[tid * 16 + q];
        const float LOG2PI = 1.8378770664093453f;
        out[(size_t)(row0 + tid) * 14 + 12] = -s - 6.0f * LOG2PI;
        out[(size_t)(row0 + tid) * 14 + 13] =  s + 6.0f + 6.0f * LOG2PI;
    }
}

// ---------------------------------------------------------------------------
extern "C" void kernel_launch(void* const* d_in, const int* in_sizes, int n_in,
                              void* d_out, int out_size, void* d_ws, size_t ws_size,
                              hipStream_t stream) {
    (void)in_sizes; (void)n_in; (void)out_size; (void)ws_size;
    const float* x    = (const float*)d_in[0];
    const int*   done = (const int*)  d_in[1];
    const float* h0   = (const float*)d_in[2];
    const float* c0   = (const float*)d_in[3];
    const float* W_ih = (const float*)d_in[4];
    const float* W_hh = (const float*)d_in[5];
    const float* b_ih = (const float*)d_in[6];
    const float* b_hh = (const float*)d_in[7];
    const float* lng  = (const float*)d_in[8];
    const float* lnb  = (const float*)d_in[9];
    const float* W1   = (const float*)d_in[10];
    const float* b1   = (const float*)d_in[11];
    const float* W2   = (const float*)d_in[12];
    const float* b2   = (const float*)d_in[13];
    const float* Wm   = (const float*)d_in[14];
    const float* bm   = (const float*)d_in[15];
    const float* Ws   = (const float*)d_in[16];
    const float* bs   = (const float*)d_in[17];
    float* out = (float*)d_out;

    // workspace carve (~37 MB; ws_size >= 135 MB confirmed)
    unsigned char* p = (unsigned char*)d_ws;
    u16* hs    = (u16*)p;              p += (size_t)(T_ + 1) * BH_ * 2;
    u16* xpad  = (u16*)p;              p += (size_t)T_ * B_ * 64 * 2;
    u16* Wcat  = (u16*)p;              p += (size_t)1024 * KP_ * 2;
    u16* W1T   = (u16*)p;              p += (size_t)M1_ * H_ * 2;
    u16* W2T   = (u16*)p;              p += (size_t)M2_ * M1_ * 2;
    u16* WhT   = (u16*)p;              p += (size_t)32 * H_ * 2;
    float* Cst = (float*)p;            p += (size_t)BH_ * 4;

    prep_xpad<<<(T_ * B_ * 8) / 256, 256, 0, stream>>>(x, xpad);
    prep_weights<<<1824, 256, 0, stream>>>(W_ih, W_hh, W1, W2, Wm, Ws,
                                           Wcat, W1T, W2T, WhT);
    init_state2<<<BH_ / 256, 256, 0, stream>>>(h0, c0, hs, Cst);

    for (int t = 0; t < T_; ++t) {
        lstm_step4<<<dim3(32, 16), 256, 0, stream>>>(
            xpad + (size_t)t * B_ * 64,
            done + (size_t)t * B_,
            hs + (size_t)t * BH_,
            hs + (size_t)(t + 1) * BH_,
            Cst, Wcat, b_ih, b_hh);
    }

    mlp_mfma64<<<(T_ * B_) / 64, 512, 0, stream>>>(
        hs + BH_, out, lng, lnb, W1T, b1, W2T, b2, WhT, bm, bs);
}

// Round 11
// 963.690 us; speedup vs baseline: 1.0751x; 1.0751x over previous
//
#include <hip/hip_runtime.h>
#include <hip/hip_bf16.h>
#include <math.h>

#define T_   64
#define B_   2048
#define OBS_ 48
#define H_   256
#define M1_  512
#define M2_  256
#define A_   12
#define BH_  (B_ * H_)
#define KP_  320   // padded K for scan: 64 (x, padded from 48) + 256 (h)

typedef unsigned short u16;
typedef __attribute__((ext_vector_type(8))) short bf16x8;
typedef __attribute__((ext_vector_type(4))) float f32x4;

static __device__ __forceinline__ u16 f2b(float f) {
    __hip_bfloat16 h = __float2bfloat16(f);
    return *reinterpret_cast<u16*>(&h);
}
static __device__ __forceinline__ float b2f(u16 u) {
    union { unsigned u32v; float f; } v; v.u32v = ((unsigned)u) << 16; return v.f;
}
static __device__ __forceinline__ float sigm(float x) {
    return 1.0f / (1.0f + __expf(-x));
}
static __device__ __forceinline__ float tanh_fast(float x) {
    x = fminf(fmaxf(x, -15.0f), 15.0f);
    float e = __expf(2.0f * x);
    return (e - 1.0f) / (e + 1.0f);
}
static __device__ __forceinline__ float elu(float x) {
    return x > 0.0f ? x : (__expf(x) - 1.0f);
}

// ---------------------------------------------------------------------------
// Pre-pass kernels
// ---------------------------------------------------------------------------
__global__ void prep_xpad(const float* __restrict__ x, u16* __restrict__ xpad) {
    const int gid = blockIdx.x * 256 + threadIdx.x;   // T*B*8 threads
    const int r = gid >> 3, k0 = (gid & 7) * 8;
    u16 tmp[8];
    if (k0 < OBS_) {
        const float4 f0 = *(const float4*)(x + (size_t)r * OBS_ + k0);
        const float4 f1 = *(const float4*)(x + (size_t)r * OBS_ + k0 + 4);
        tmp[0] = f2b(f0.x); tmp[1] = f2b(f0.y); tmp[2] = f2b(f0.z); tmp[3] = f2b(f0.w);
        tmp[4] = f2b(f1.x); tmp[5] = f2b(f1.y); tmp[6] = f2b(f1.z); tmp[7] = f2b(f1.w);
    } else {
        #pragma unroll
        for (int i = 0; i < 8; ++i) tmp[i] = 0;
    }
    *(uint4*)(xpad + (size_t)gid * 8) = *(uint4*)tmp;
}

__global__ void prep_weights(const float* __restrict__ W_ih, const float* __restrict__ W_hh,
                             const float* __restrict__ W1,  const float* __restrict__ W2,
                             const float* __restrict__ Wm,  const float* __restrict__ Ws,
                             u16* __restrict__ Wcat, u16* __restrict__ W1T,
                             u16* __restrict__ W2T,  u16* __restrict__ WhT) {
    const int b = blockIdx.x, tid = threadIdx.x;
    if (b < 1024) {
        for (int k = tid; k < KP_; k += 256) {
            float v;
            if (k < OBS_)    v = W_ih[b * OBS_ + k];
            else if (k < 64) v = 0.0f;
            else             v = W_hh[b * H_ + (k - 64)];
            Wcat[b * KP_ + k] = f2b(v);
        }
    } else if (b < 1536) {
        const int n = b - 1024;                       // W1T [512][256]
        W1T[n * 256 + tid] = f2b(W1[tid * M1_ + n]);
    } else if (b < 1792) {
        const int n = b - 1536;                       // W2T [256][512]
        W2T[n * 512 + tid]       = f2b(W2[tid * M2_ + n]);
        W2T[n * 512 + tid + 256] = f2b(W2[(tid + 256) * M2_ + n]);
    } else {
        const int n = b - 1792;                       // WhT [32][256]
        float v = 0.0f;
        if (n < 12)                 v = Wm[tid * A_ + n];
        else if (n >= 16 && n < 28) v = Ws[tid * A_ + (n - 16)];
        WhT[n * 256 + tid] = f2b(v);
    }
}

__global__ void init_state2(const float* __restrict__ h0, const float* __restrict__ c0,
                            u16* __restrict__ hs0, float* __restrict__ Cst) {
    const int i = blockIdx.x * 256 + threadIdx.x;
    hs0[i] = f2b(h0[i]);
    Cst[i] = c0[i];
}

// ---------------------------------------------------------------------------
// LSTM step (round-4/7 kernel, known-good ~11.25 us/step incl. dispatch).
// Grid (32,16): block = 64 b-rows x (4 gates x 16 j), 4 waves of 32x32.
// ---------------------------------------------------------------------------
#define ASM_(row, chunk) (a_sm + (size_t)(row) * 320 + (size_t)(((chunk) ^ ((row) & 7)) << 3))

__global__ __launch_bounds__(256, 2) void lstm_step4(
    const u16*  __restrict__ xpad_t,  // [B][64]
    const int*  __restrict__ done_t,  // [B]
    const u16*  __restrict__ Hin,     // [B][256] bf16
    u16*        __restrict__ Hout,    // [B][256] bf16
    float*      __restrict__ Cst,     // [B][256] fp32, in-place
    const u16*  __restrict__ Wcat,    // [1024][320]
    const float* __restrict__ b_ih,
    const float* __restrict__ b_hh)
{
    __shared__ u16   a_sm[64 * 320];   // 40 KB, XOR-swizzled
    __shared__ float g_sm[64][68];     // 17.4 KB
    __shared__ float keep_sm[64];

    const int tid  = threadIdx.x;
    const int lane = tid & 63;
    const int wave = tid >> 6;
    const int wm = wave & 1, wn = wave >> 1;
    const int quad = lane >> 4, l16 = lane & 15;
    const int b0 = blockIdx.x * 64;
    const int j0 = blockIdx.y * 16;

    // ---- preload B fragments (20 frags = 80 VGPRs; Wcat is L2-resident) ----
    bf16x8 Bf0[10], Bf1[10];
    {
        const u16* wp0 = Wcat + ((size_t)((wn * 2 + 0) * 256 + j0 + l16)) * KP_ + quad * 8;
        const u16* wp1 = Wcat + ((size_t)((wn * 2 + 1) * 256 + j0 + l16)) * KP_ + quad * 8;
        #pragma unroll
        for (int kt = 0; kt < 10; ++kt) {
            Bf0[kt] = *(const bf16x8*)(wp0 + kt * 32);
            Bf1[kt] = *(const bf16x8*)(wp1 + kt * 32);
        }
    }

    // ---- stage A tile: whole K=320 in one shot ----
    if (tid < 64) keep_sm[tid] = done_t[b0 + tid] ? 0.0f : 1.0f;
    {
        const int srow = tid >> 2;     // 0..63
        const int sseg = tid & 3;      // 0..3
        const u16* xrow = xpad_t + (size_t)(b0 + srow) * 64;
        const uint4 xv0 = *(const uint4*)(xrow + sseg * 8);
        const uint4 xv1 = *(const uint4*)(xrow + (sseg + 4) * 8);
        *(uint4*)ASM_(srow, sseg)     = xv0;
        *(uint4*)ASM_(srow, sseg + 4) = xv1;

        const int dn = done_t[b0 + srow];
        const u16* hrow = Hin + (size_t)(b0 + srow) * H_ + sseg * 64;
        #pragma unroll
        for (int i = 0; i < 8; ++i) {
            uint4 hv = *(const uint4*)(hrow + i * 8);
            if (dn) hv = make_uint4(0u, 0u, 0u, 0u);
            *(uint4*)ASM_(srow, 8 + sseg * 8 + i) = hv;
        }
    }
    __syncthreads();

    // ---- 40 MFMA per wave ----
    f32x4 acc00 = {0,0,0,0}, acc01 = {0,0,0,0}, acc10 = {0,0,0,0}, acc11 = {0,0,0,0};
    #pragma unroll
    for (int kt = 0; kt < 10; ++kt) {
        const bf16x8 af0 = *(const bf16x8*)ASM_(wm * 32 +  0 + l16, kt * 4 + quad);
        const bf16x8 af1 = *(const bf16x8*)ASM_(wm * 32 + 16 + l16, kt * 4 + quad);
        acc00 = __builtin_amdgcn_mfma_f32_16x16x32_bf16(af0, Bf0[kt], acc00, 0, 0, 0);
        acc01 = __builtin_amdgcn_mfma_f32_16x16x32_bf16(af0, Bf1[kt], acc01, 0, 0, 0);
        acc10 = __builtin_amdgcn_mfma_f32_16x16x32_bf16(af1, Bf0[kt], acc10, 0, 0, 0);
        acc11 = __builtin_amdgcn_mfma_f32_16x16x32_bf16(af1, Bf1[kt], acc11, 0, 0, 0);
    }

    // ---- accs -> LDS for cross-wave gate fusion ----
    #pragma unroll
    for (int r = 0; r < 4; ++r) {
        g_sm[wm * 32 +  0 + quad * 4 + r][wn * 32 +  0 + l16] = acc00[r];
        g_sm[wm * 32 +  0 + quad * 4 + r][wn * 32 + 16 + l16] = acc01[r];
        g_sm[wm * 32 + 16 + quad * 4 + r][wn * 32 +  0 + l16] = acc10[r];
        g_sm[wm * 32 + 16 + quad * 4 + r][wn * 32 + 16 + l16] = acc11[r];
    }
    __syncthreads();

    // ---- epilogue: gates -> c (fp32 global), h -> Hout (bf16) ----
    const int jj = tid & 15, bq = tid >> 4;
    const int jg = j0 + jj;
    const float bi_b = b_ih[jg]       + b_hh[jg];
    const float bf_b = b_ih[256 + jg] + b_hh[256 + jg];
    const float bg_b = b_ih[512 + jg] + b_hh[512 + jg];
    const float bo_b = b_ih[768 + jg] + b_hh[768 + jg];
    #pragma unroll
    for (int r = 0; r < 4; ++r) {
        const int b = bq * 4 + r;
        const float gi = g_sm[b][jj]      + bi_b;
        const float gf = g_sm[b][16 + jj] + bf_b;
        const float gg = g_sm[b][32 + jj] + bg_b;
        const float go = g_sm[b][48 + jj] + bo_b;
        const size_t idx = (size_t)(b0 + b) * H_ + jg;
        const float cold = Cst[idx] * keep_sm[b];
        const float cn = sigm(gf) * cold + sigm(gi) * tanh_fast(gg);
        Cst[idx] = cn;
        Hout[idx] = f2b(sigm(go) * tanh_fast(cn));
    }
}

// ---------------------------------------------------------------------------
// MLP v5: 128 rows/block (halves weight re-traffic vs round-7's 64-row tile,
// the lever that gave r2->r7's 277->229). 512 threads, 8 waves; dynamic LDS
// 128 KB (2 x 128x256 u16 buffers, SY swizzle — bank conflicts proven to be a
// red herring in r10: SQ_LDS_BANK_CONFLICT invariant across layouts, comes
// from the LN shfl ops and is 2-way/free). No ring prefetch (r9: compiler
// re-sinks it; neutral-to-negative).
// ---------------------------------------------------------------------------
#define SY(row, col) ((size_t)(row) * 256 + ((((col) >> 3) ^ ((row) & 7)) << 3) + ((col) & 7))

__global__ __launch_bounds__(512, 2) void mlp_mfma128(
    const u16*  __restrict__ hs,    // [nrows][256] bf16
    float*      __restrict__ out,   // [nrows][14]
    const float* __restrict__ lng, const float* __restrict__ lnb,
    const u16*  __restrict__ W1T, const float* __restrict__ b1,
    const u16*  __restrict__ W2T, const float* __restrict__ b2,
    const u16*  __restrict__ WhT,
    const float* __restrict__ bm, const float* __restrict__ bs)
{
    extern __shared__ u16 smem[];
    u16* ybf = smem;                 // [128*256]: LN output, later y2
    u16* yh  = smem + 128 * 256;     // [128*256]: y1 column-half; later ls overlay

    const int tid  = threadIdx.x;
    const int lane = tid & 63;
    const int wave = tid >> 6;        // 0..7
    const int quad = lane >> 4, l16 = lane & 15;
    const int row0 = blockIdx.x * 128;

    // ---- LayerNorm: wave w -> rows w*16..w*16+15; lane holds 4 cols ----
    {
        const float4 gv = *(const float4*)(lng + lane * 4);
        const float4 bv = *(const float4*)(lnb + lane * 4);
        #pragma unroll
        for (int rr = 0; rr < 16; ++rr) {
            const int r = wave * 16 + rr;
            const ushort4 hv = *(const ushort4*)(hs + (size_t)(row0 + r) * H_ + lane * 4);
            const float v0 = b2f(hv.x), v1 = b2f(hv.y), v2 = b2f(hv.z), v3 = b2f(hv.w);
            float s  = v0 + v1 + v2 + v3;
            float ss = v0 * v0 + v1 * v1 + v2 * v2 + v3 * v3;
            #pragma unroll
            for (int off = 32; off > 0; off >>= 1) {
                s  += __shfl_down(s,  off);
                ss += __shfl_down(ss, off);
            }
            s = __shfl(s, 0); ss = __shfl(ss, 0);
            const float mu   = s * (1.0f / 256.0f);
            const float rstd = rsqrtf(ss * (1.0f / 256.0f) - mu * mu + 1e-5f);
            ushort4 o;
            o.x = f2b((v0 - mu) * rstd * gv.x + bv.x);
            o.y = f2b((v1 - mu) * rstd * gv.y + bv.y);
            o.z = f2b((v2 - mu) * rstd * gv.z + bv.z);
            o.w = f2b((v3 - mu) * rstd * gv.w + bv.w);
            *(ushort4*)(ybf + SY(r, lane * 4)) = o;
        }
    }
    __syncthreads();

    // ---- L2 partial accumulators: live across both phases (8 m-frags) ----
    f32x4 acc2[8][2];
    #pragma unroll
    for (int m = 0; m < 8; ++m)
        #pragma unroll
        for (int j = 0; j < 2; ++j) acc2[m][j] = (f32x4){0,0,0,0};

    #pragma unroll
    for (int ph = 0; ph < 2; ++ph) {
        // ---- L1 phase: y1 cols [ph*256 + wave*32, +32) for all 128 rows ----
        {
            f32x4 acc[8][2];
            #pragma unroll
            for (int m = 0; m < 8; ++m)
                #pragma unroll
                for (int j = 0; j < 2; ++j) acc[m][j] = (f32x4){0,0,0,0};
            const int n0 = ph * 256 + wave * 32;
            const u16* wp0 = W1T + (size_t)(n0 + l16) * 256 + quad * 8;
            const u16* wp1 = W1T + (size_t)(n0 + 16 + l16) * 256 + quad * 8;
            #pragma unroll
            for (int kt = 0; kt < 8; ++kt) {
                const int k0 = kt * 32;
                const bf16x8 bw0 = *(const bf16x8*)(wp0 + k0);
                const bf16x8 bw1 = *(const bf16x8*)(wp1 + k0);
                #pragma unroll
                for (int m = 0; m < 8; ++m) {
                    const bf16x8 af = *(const bf16x8*)(ybf + SY(m * 16 + l16, k0 + quad * 8));
                    acc[m][0] = __builtin_amdgcn_mfma_f32_16x16x32_bf16(af, bw0, acc[m][0], 0, 0, 0);
                    acc[m][1] = __builtin_amdgcn_mfma_f32_16x16x32_bf16(af, bw1, acc[m][1], 0, 0, 0);
                }
            }
            const float bb0 = b1[n0 + l16], bb1 = b1[n0 + 16 + l16];
            __syncthreads();   // yh free (prev phase consumed / first use)
            #pragma unroll
            for (int m = 0; m < 8; ++m)
                #pragma unroll
                for (int r = 0; r < 4; ++r) {
                    const int row = m * 16 + quad * 4 + r;
                    yh[SY(row, wave * 32 + l16)]      = f2b(elu(acc[m][0][r] + bb0));
                    yh[SY(row, wave * 32 + 16 + l16)] = f2b(elu(acc[m][1][r] + bb1));
                }
        }
        __syncthreads();

        // ---- L2 partial: K in [ph*256, +256); wave n-slice 32 cols ----
        {
            const int n0 = wave * 32;
            const u16* wp0 = W2T + (size_t)(n0 + l16) * 512 + ph * 256 + quad * 8;
            const u16* wp1 = W2T + (size_t)(n0 + 16 + l16) * 512 + ph * 256 + quad * 8;
            #pragma unroll
            for (int kt = 0; kt < 8; ++kt) {
                const int k0 = kt * 32;
                const bf16x8 bw0 = *(const bf16x8*)(wp0 + k0);
                const bf16x8 bw1 = *(const bf16x8*)(wp1 + k0);
                #pragma unroll
                for (int m = 0; m < 8; ++m) {
                    const bf16x8 af = *(const bf16x8*)(yh + SY(m * 16 + l16, k0 + quad * 8));
                    acc2[m][0] = __builtin_amdgcn_mfma_f32_16x16x32_bf16(af, bw0, acc2[m][0], 0, 0, 0);
                    acc2[m][1] = __builtin_amdgcn_mfma_f32_16x16x32_bf16(af, bw1, acc2[m][1], 0, 0, 0);
                }
            }
        }
        __syncthreads();
    }

    // ---- y2 = elu(acc2 + b2) -> ybf (LN data fully consumed) ----
    {
        const float bb0 = b2[wave * 32 + l16], bb1 = b2[wave * 32 + 16 + l16];
        #pragma unroll
        for (int m = 0; m < 8; ++m)
            #pragma unroll
            for (int r = 0; r < 4; ++r) {
                const int row = m * 16 + quad * 4 + r;
                ybf[SY(row, wave * 32 + l16)]      = f2b(elu(acc2[m][0][r] + bb0));
                ybf[SY(row, wave * 32 + 16 + l16)] = f2b(elu(acc2[m][1][r] + bb1));
            }
    }
    __syncthreads();

    // ---- Heads: wave = m-frag (8 waves x 16 rows); mean + logstd ----
    float* lsf = (float*)yh;   // overlay: [128][16] floats (yh free)
    {
        f32x4 a0 = {0,0,0,0}, a1 = {0,0,0,0};
        const u16* wp0 = WhT + (size_t)l16 * 256 + quad * 8;          // mean rows 0..15
        const u16* wp1 = WhT + (size_t)(16 + l16) * 256 + quad * 8;   // logstd rows 16..31
        #pragma unroll
        for (int kt = 0; kt < 8; ++kt) {
            const int k0 = kt * 32;
            const bf16x8 af  = *(const bf16x8*)(ybf + SY(wave * 16 + l16, k0 + quad * 8));
            const bf16x8 bw0 = *(const bf16x8*)(wp0 + k0);
            const bf16x8 bw1 = *(const bf16x8*)(wp1 + k0);
            a0 = __builtin_amdgcn_mfma_f32_16x16x32_bf16(af, bw0, a0, 0, 0, 0);
            a1 = __builtin_amdgcn_mfma_f32_16x16x32_bf16(af, bw1, a1, 0, 0, 0);
        }
        if (l16 < 12) {
            const float bbm = bm[l16], bbs = bs[l16];
            #pragma unroll
            for (int r = 0; r < 4; ++r) {
                const int row = wave * 16 + quad * 4 + r;
                out[(size_t)(row0 + row) * 14 + l16] = a0[r] + bbm;
                lsf[row * 16 + l16] = fminf(fmaxf(a1[r] + bbs, -5.0f), 2.0f);
            }
        }
    }
    __syncthreads();
    if (tid < 128) {
        float s = 0.0f;
        #pragma unroll
        for (int q = 0; q < 12; ++q) s += lsf[tid * 16 + q];
        const float LOG2PI = 1.8378770664093453f;
        out[(size_t)(row0 + tid) * 14 + 12] = -s - 6.0f * LOG2PI;
        out[(size_t)(row0 + tid) * 14 + 13] =  s + 6.0f + 6.0f * LOG2PI;
    }
}

// ---------------------------------------------------------------------------
extern "C" void kernel_launch(void* const* d_in, const int* in_sizes, int n_in,
                              void* d_out, int out_size, void* d_ws, size_t ws_size,
                              hipStream_t stream) {
    (void)in_sizes; (void)n_in; (void)out_size; (void)ws_size;
    const float* x    = (const float*)d_in[0];
    const int*   done = (const int*)  d_in[1];
    const float* h0   = (const float*)d_in[2];
    const float* c0   = (const float*)d_in[3];
    const float* W_ih = (const float*)d_in[4];
    const float* W_hh = (const float*)d_in[5];
    const float* b_ih = (const float*)d_in[6];
    const float* b_hh = (const float*)d_in[7];
    const float* lng  = (const float*)d_in[8];
    const float* lnb  = (const float*)d_in[9];
    const float* W1   = (const float*)d_in[10];
    const float* b1   = (const float*)d_in[11];
    const float* W2   = (const float*)d_in[12];
    const float* b2   = (const float*)d_in[13];
    const float* Wm   = (const float*)d_in[14];
    const float* bm   = (const float*)d_in[15];
    const float* Ws   = (const float*)d_in[16];
    const float* bs   = (const float*)d_in[17];
    float* out = (float*)d_out;

    // workspace carve (~37 MB; ws_size >= 135 MB confirmed)
    unsigned char* p = (unsigned char*)d_ws;
    u16* hs    = (u16*)p;              p += (size_t)(T_ + 1) * BH_ * 2;
    u16* xpad  = (u16*)p;              p += (size_t)T_ * B_ * 64 * 2;
    u16* Wcat  = (u16*)p;              p += (size_t)1024 * KP_ * 2;
    u16* W1T   = (u16*)p;              p += (size_t)M1_ * H_ * 2;
    u16* W2T   = (u16*)p;              p += (size_t)M2_ * M1_ * 2;
    u16* WhT   = (u16*)p;              p += (size_t)32 * H_ * 2;
    float* Cst = (float*)p;            p += (size_t)BH_ * 4;

    // allow 128 KB dynamic LDS for the MLP (idempotent, graph-capture-safe)
    hipFuncSetAttribute((const void*)mlp_mfma128,
                        hipFuncAttributeMaxDynamicSharedMemorySize, 131072);

    prep_xpad<<<(T_ * B_ * 8) / 256, 256, 0, stream>>>(x, xpad);
    prep_weights<<<1824, 256, 0, stream>>>(W_ih, W_hh, W1, W2, Wm, Ws,
                                           Wcat, W1T, W2T, WhT);
    init_state2<<<BH_ / 256, 256, 0, stream>>>(h0, c0, hs, Cst);

    for (int t = 0; t < T_; ++t) {
        lstm_step4<<<dim3(32, 16), 256, 0, stream>>>(
            xpad + (size_t)t * B_ * 64,
            done + (size_t)t * B_,
            hs + (size_t)t * BH_,
            hs + (size_t)(t + 1) * BH_,
            Cst, Wcat, b_ih, b_hh);
    }

    mlp_mfma128<<<(T_ * B_) / 128, 512, 131072, stream>>>(
        hs + BH_, out, lng, lnb, W1T, b1, W2T, b2, WhT, bm, bs);
}